// Round 15
// baseline (295.083 us; speedup 1.0000x reference)
//
#include <hip/hip_runtime.h>
#include <hip/hip_bf16.h>
#include <math.h>
#include <stdint.h>

#define B_ 4
#define D_ 64
#define H_ 64
#define W_ 64
#define S_ 64
#define N_ 8192
#define K_ 4
#define HID_ 256
#define HW_ 4096
#define NQ_ (B_*N_)        // 32768 queries
#define ROWS_ (NQ_*8)      // 262144 MLP rows (4 attn + 4 local per query)

typedef _Float16 h8   __attribute__((ext_vector_type(8)));
typedef _Float16 h4   __attribute__((ext_vector_type(4)));
typedef __fp16   pk2  __attribute__((ext_vector_type(2)));   // cvt_pkrtz native type
typedef float    f32x4 __attribute__((ext_vector_type(4)));

// ---------------------------------------------------------------------------
// fused prep (R10 structure, measured-best): [0,256) feat transpose |
// [256,512) attn transpose | [512,1863) weight repack | [1863,1927) segmax.
// ---------------------------------------------------------------------------
__global__ void fused_prep_kernel(const float* __restrict__ feat,
                                  const float* __restrict__ attn,
                                  const float* __restrict__ w0,
                                  const float* __restrict__ w1,
                                  const float* __restrict__ w2,
                                  const float* __restrict__ w3,
                                  const float* __restrict__ w4,
                                  _Float16* __restrict__ featT,
                                  float* __restrict__ attnT,
                                  _Float16* __restrict__ w0F,
                                  _Float16* __restrict__ wF123,
                                  float* __restrict__ w4T,
                                  float* __restrict__ w0tail,
                                  int* __restrict__ segm)
{
  __shared__ float t[64][65];
  int blk = blockIdx.x;
  int tid = threadIdx.x;

  if (blk < 256) {                       // ---- feat (B,D,H,W) -> featT[b][y][x][c]
    int b = blk >> 6, y = blk & 63;
    for (int p = 0; p < 16; ++p) {
      int c = p * 4 + (tid >> 6), x = tid & 63;
      t[c][x] = feat[(((size_t)b * 64 + c) << 12) + (y << 6) + x];
    }
    __syncthreads();
    for (int p = 0; p < 16; ++p) {
      int x = p * 4 + (tid >> 6), c = tid & 63;
      featT[((((size_t)b * 64 + y) * 64 + x) << 6) + c] = (_Float16)t[c][x];
    }
    return;
  }
  blk -= 256;
  if (blk < 256) {                       // ---- attn (B,HW,S) -> attnT (B,S,HW)
    int b = blk >> 6, j0 = (blk & 63) << 6;
    for (int idx = tid; idx < 4096; idx += 256) {
      int r = idx >> 6, c = idx & 63;
      t[r][c] = attn[((size_t)(b * 4096 + j0 + r)) * 64 + c];
    }
    __syncthreads();
    for (int idx = tid; idx < 4096; idx += 256) {
      int s = idx >> 6, r = idx & 63;
      attnT[((size_t)(b * 64 + s)) * 4096 + j0 + r] = t[r][s];
    }
    return;
  }
  blk -= 256;
  if (blk < 1351) {                      // ---- fragment-linear weights
    int i = blk * 256 + tid;
    if (i < 147456) {                    // w0F
      int g = i / 36864, rem = i - g * 36864;
      int ks = rem >> 11, rem2 = rem & 2047;
      int cb = rem2 >> 9, e = rem2 & 511;
      int lane = e >> 3, j = e & 7;
      int n = g * 64 + cb * 16 + (lane & 15);
      int k = ks * 32 + (lane >> 4) * 8 + j;       // reordered k = kk*64+cc
      int kk = k >> 6, cc = k & 63;
      w0F[i] = (_Float16)w0[(cc * 9 + kk) * 256 + n];
      return;
    }
    i -= 147456;
    if (i < 196608) {                    // wF123
      int l = i >> 16, rem = i & 65535;
      int g = rem >> 14, rem2 = rem & 16383;
      int ks = rem2 >> 11, rem3 = rem2 & 2047;
      int cb = rem3 >> 9, e = rem3 & 511;
      int lane = e >> 3, j = e & 7;
      int n = g * 64 + cb * 16 + (lane & 15);
      int k = ks * 32 + (lane >> 4) * 8 + j;
      const float* w = (l == 0) ? w1 : (l == 1) ? w2 : w3;
      wF123[i] = (_Float16)w[k * 256 + n];
      return;
    }
    i -= 196608;
    if (i < 768) { int j = i / 256, c = i - j * 256; w4T[i] = w4[c * 3 + j]; return; }
    i -= 768;
    if (i < 1024) { int j = i >> 8, n = i & 255; w0tail[i] = w0[(576 + j) * 256 + n]; }
    return;
  }
  blk -= 1351;
  {                                      // ---- segmax (64 blocks)
    int p = blk * 256 + tid;
    if (p >= B_ * HW_) return;
    const float* a = attn + (size_t)p * S_;
    float best = a[0]; int bi = 0;
    for (int s = 1; s < S_; ++s) { float v = a[s]; if (v > best) { best = v; bi = s; } }
    segm[p] = bi;
  }
}

// ---------------------------------------------------------------------------
// topk v2: one wave per (b,s). u64 key = (float_bits << 32) | (~idx):
// for positive softmax values, key order == (value desc, idx asc) — exactly
// jax.lax.top_k tie semantics. Lane-local sorted-4 scan + 6-stage shfl_xor
// butterfly merge (disjoint lane groups => no duplicate keys). Barrier-free.
// ---------------------------------------------------------------------------
__device__ inline void topk_insert(unsigned long long key,
                                   unsigned long long& k0, unsigned long long& k1,
                                   unsigned long long& k2, unsigned long long& k3)
{
  if (key > k3) {
    if (key > k0)      { k3 = k2; k2 = k1; k1 = k0; k0 = key; }
    else if (key > k1) { k3 = k2; k2 = k1; k1 = key; }
    else if (key > k2) { k3 = k2; k2 = key; }
    else               { k3 = key; }
  }
}

__global__ void topk_kernel(const float* __restrict__ attnT,
                            int* __restrict__ refc, float* __restrict__ wprob)
{
  int wv = threadIdx.x >> 6, lane = threadIdx.x & 63;
  int bid = blockIdx.x * 4 + wv;        // b*64 + s, 64 blocks x 4 waves
  const float* col = attnT + (size_t)bid * 4096;

  unsigned long long k0 = 0, k1 = 0, k2 = 0, k3 = 0;
  for (int it = 0; it < 64; ++it) {
    int j = it * 64 + lane;
    unsigned vb = __builtin_bit_cast(unsigned, col[j]);
    unsigned long long key = ((unsigned long long)vb << 32) | (unsigned)(0xFFFFFFFFu - j);
    topk_insert(key, k0, k1, k2, k3);
  }
  #pragma unroll
  for (int st = 1; st < 64; st <<= 1) {
    unsigned long long p0 = __shfl_xor(k0, st, 64);
    unsigned long long p1 = __shfl_xor(k1, st, 64);
    unsigned long long p2 = __shfl_xor(k2, st, 64);
    unsigned long long p3 = __shfl_xor(k3, st, 64);
    topk_insert(p0, k0, k1, k2, k3);
    topk_insert(p1, k0, k1, k2, k3);
    topk_insert(p2, k0, k1, k2, k3);
    topk_insert(p3, k0, k1, k2, k3);
  }
  if (lane == 0) {
    unsigned long long ks[4] = { k0, k1, k2, k3 };
    float vs[4]; int is[4];
    #pragma unroll
    for (int k = 0; k < 4; ++k) {
      vs[k] = __builtin_bit_cast(float, (unsigned)(ks[k] >> 32));
      is[k] = (int)(0xFFFFFFFFu - (unsigned)(ks[k] & 0xFFFFFFFFu));
    }
    float ssum = vs[0] + vs[1] + vs[2] + vs[3];
    #pragma unroll
    for (int k = 0; k < 4; ++k) { refc[bid*4 + k] = is[k]; wprob[bid*4 + k] = vs[k] / ssum; }
  }
}

// ---------------------------------------------------------------------------
// P0 GEMM (f16 MFMA, f16 out): 512 blocks = (b, y, half-row of 32 px).
// ---------------------------------------------------------------------------
__launch_bounds__(256, 2)
__global__ void p0_kernel(const _Float16* __restrict__ featT,
                          const _Float16* __restrict__ w0F,
                          _Float16* __restrict__ P0h)
{
  int blk = blockIdx.x;                 // b*128 + y*2 + hr
  int b = blk >> 7, y = (blk >> 1) & 63, hr = blk & 1;
  int tid = threadIdx.x;
  int wave = tid >> 6, lane = tid & 63, quad = lane >> 4, l16 = lane & 15;

  f32x4 acc[2][4];
  #pragma unroll
  for (int i = 0; i < 2; i++)
    #pragma unroll
    for (int j = 0; j < 4; j++) { f32x4 z = {0.f,0.f,0.f,0.f}; acc[i][j] = z; }
  h8 zero8 = {0,0,0,0,0,0,0,0};

  #pragma unroll
  for (int ks = 0; ks < 18; ++ks) {     // K = 576 = 18*32
    int k0 = ks * 32 + quad * 8;
    int kk = k0 >> 6, cc = k0 & 63;
    int di = kk / 3 - 1, dj = kk - (kk / 3) * 3 - 1;
    int yy = y + di;
    h8 afr[2];
    #pragma unroll
    for (int rb = 0; rb < 2; rb++) {
      int xx = hr * 32 + rb * 16 + l16 + dj;
      if ((unsigned)yy < 64u && (unsigned)xx < 64u)
        afr[rb] = *(const h8*)(featT + ((((size_t)b * 64 + yy) * 64 + xx) << 6) + cc);
      else
        afr[rb] = zero8;
    }
    h8 bfr[4];
    #pragma unroll
    for (int cb = 0; cb < 4; cb++)
      bfr[cb] = *(const h8*)(w0F + ((((size_t)wave * 18 + ks) * 4 + cb) << 9) + lane * 8);
    #pragma unroll
    for (int rb = 0; rb < 2; rb++)
      #pragma unroll
      for (int cb = 0; cb < 4; cb++)
        acc[rb][cb] = __builtin_amdgcn_mfma_f32_16x16x32_f16(afr[rb], bfr[cb], acc[rb][cb], 0, 0, 0);
  }
  int pixbase = b * 4096 + y * 64 + hr * 32;
  #pragma unroll
  for (int rb = 0; rb < 2; rb++)
    #pragma unroll
    for (int cb = 0; cb < 4; cb++)
      #pragma unroll
      for (int i = 0; i < 4; i++) {
        int m = rb * 16 + quad * 4 + i;
        int n = wave * 64 + cb * 16 + l16;
        P0h[((size_t)(pixbase + m) << 8) + n] = (_Float16)acc[rb][cb][i];
      }
}

// ---------------------------------------------------------------------------
// Fused MLP trunk, M=128 (f16 MFMA): meta fused into preamble (threads 0..15
// compute their 16 queries' 8-row descriptors into LDS — kills the meta
// kernel + 12.6 MB round-trip); seed reads LDS; acc init = bias; pkrtz
// writeback; epilogue v2 (measured-best).
// ---------------------------------------------------------------------------
__launch_bounds__(256, 2)
__global__ void trunk_kernel(const _Float16* __restrict__ P0h,
                             const float* __restrict__ coord,
                             const float* __restrict__ cell,
                             const int* __restrict__ segm,
                             const int* __restrict__ refc,
                             const float* __restrict__ wprob,
                             const float* __restrict__ w0tail,
                             const float* __restrict__ b0,
                             const _Float16* __restrict__ wF123,
                             const float* __restrict__ b1,
                             const float* __restrict__ b2,
                             const float* __restrict__ b3,
                             const float* __restrict__ w4T,
                             const float* __restrict__ b4,
                             float* __restrict__ out)
{
  __shared__ _Float16 hS[128][264];     // +8 pad; 67.6 KB
  __shared__ float  mwL[128];
  __shared__ int    msrcL[128];
  __shared__ float4 mtL[128];
  __shared__ float  swL[16];
  __shared__ float  partB[16][3][4];

  int tid = threadIdx.x;
  int rowbase = blockIdx.x * 128;
  int wv = tid >> 6;

  // ---- meta preamble: threads 0..15 build 8 row descriptors each ----
  if (tid < 16) {
    int q = blockIdx.x * 16 + tid;
    int b = q >> 13;
    float c0 = coord[2*q], c1 = coord[2*q + 1];
    float rc0 = cell[2*q] * 64.0f, rc1 = cell[2*q + 1] * 64.0f;   // rel_cell

    // attention branch
    float pf0 = (c0 + 1.0f) / 2.0f * 64.0f;
    float pf1 = (c1 + 1.0f) / 2.0f * 64.0f;
    int pc0 = (int)pf0, pc1 = (int)pf1;         // trunc (non-negative)
    pc0 = min(max(pc0, 0), 4095); pc1 = min(max(pc1, 0), 4095);
    int pc1d = pc0 * 64 + pc1;
    int sg = segm[b * 4096 + min(pc1d, 4095)];
    int base = (b * 64 + sg) * 4;
    #pragma unroll
    for (int k = 0; k < 4; ++k) {
      int rc = refc[base + k];
      int rrc = rc - pc1d;
      float rel0 = (float)(rrc >> 6) * 0.015625f;   // floor-div 64 then /64
      float rel1 = (float)(rrc & 63) * 0.015625f;
      int rr = tid * 8 + k;
      msrcL[rr] = rc;                              // batch-0 gather (faithful)
      mtL[rr] = make_float4(rel0, rel1, rc0, rc1);
      mwL[rr] = 0.5f * wprob[base + k];
    }

    // local ensemble branch
    const float sg0[4] = { -1.f, -1.f, 1.f, 1.f };
    const float sg1[4] = { -1.f,  1.f, -1.f, 1.f };
    float area[4], rr0[4], rr1[4]; int srcs[4];
    #pragma unroll
    for (int t = 0; t < 4; ++t) {
      float o0 = sg0[t] * 0.015625f + 1e-6f;
      float o1 = sg1[t] * 0.015625f + 1e-6f;
      float cc0 = fminf(fmaxf(c0 + o0, -1.0f + 1e-6f), 1.0f - 1e-6f);
      float cc1 = fminf(fmaxf(c1 + o1, -1.0f + 1e-6f), 1.0f - 1e-6f);
      float vy = ((cc0 + 1.0f) * 64.0f - 1.0f) / 2.0f;
      float vx = ((cc1 + 1.0f) * 64.0f - 1.0f) / 2.0f;
      float fy = fminf(fmaxf(rintf(vy), 0.0f), 63.0f);   // rint then clip
      float fx = fminf(fmaxf(rintf(vx), 0.0f), 63.0f);
      int iy = (int)fy, ix = (int)fx;
      srcs[t] = b * 4096 + iy * 64 + ix;
      float qc0 = -1.0f + (2.0f * (float)iy + 1.0f) / 64.0f;
      float qc1 = -1.0f + (2.0f * (float)ix + 1.0f) / 64.0f;
      float r0 = (c0 - qc0) * 64.0f;
      float r1 = (c1 - qc1) * 64.0f;
      rr0[t] = r0; rr1[t] = r1;
      area[t] = fabsf(r0 * r1) + 1e-9f;
    }
    float tot = area[0] + area[1] + area[2] + area[3];
    #pragma unroll
    for (int t = 0; t < 4; ++t) {
      int rr = tid * 8 + 4 + t;
      msrcL[rr] = srcs[t];
      mtL[rr] = make_float4(rr0[t], rr1[t], rc0, rc1);
      mwL[rr] = 0.5f * area[3 - t] / tot;          // wts = area[::-1]/tot
    }
  }
  __syncthreads();

  // ---- seed: h0 = relu(P0h[src] + t . w0tail + b0); 8-deep batched gather ----
  {
    int cg = tid & 63;
    float4 wt0 = ((const float4*)w0tail)[cg];
    float4 wt1 = ((const float4*)w0tail)[64 + cg];
    float4 wt2 = ((const float4*)w0tail)[128 + cg];
    float4 wt3 = ((const float4*)w0tail)[192 + cg];
    float4 bb  = ((const float4*)b0)[cg];
    #pragma unroll 1
    for (int g = 0; g < 4; ++g) {
      int srcs[8]; float4 ts[8];
      #pragma unroll
      for (int i = 0; i < 8; ++i) {
        int rr_ = g * 32 + i * 4 + wv;
        srcs[i] = msrcL[rr_];
        ts[i] = mtL[rr_];
      }
      #pragma unroll
      for (int i = 0; i < 8; ++i) {
        int rr = g * 32 + i * 4 + wv;
        float4 t = ts[i];
        h4 pvv = *(const h4*)(P0h + ((size_t)srcs[i] << 8) + cg * 4);
        float v0 = fmaxf((float)pvv[0] + t.x*wt0.x + t.y*wt1.x + t.z*wt2.x + t.w*wt3.x + bb.x, 0.0f);
        float v1 = fmaxf((float)pvv[1] + t.x*wt0.y + t.y*wt1.y + t.z*wt2.y + t.w*wt3.y + bb.y, 0.0f);
        float v2 = fmaxf((float)pvv[2] + t.x*wt0.z + t.y*wt1.z + t.z*wt2.z + t.w*wt3.z + bb.z, 0.0f);
        float v3 = fmaxf((float)pvv[3] + t.x*wt0.w + t.y*wt1.w + t.z*wt2.w + t.w*wt3.w + bb.w, 0.0f);
        pk2 a01 = __builtin_amdgcn_cvt_pkrtz(v0, v1);
        pk2 a23 = __builtin_amdgcn_cvt_pkrtz(v2, v3);
        int2 packed;
        packed.x = __builtin_bit_cast(int, a01);
        packed.y = __builtin_bit_cast(int, a23);
        *(int2*)(&hS[rr][cg * 4]) = packed;
      }
    }
  }
  __syncthreads();

  int wave = tid >> 6, lane = tid & 63, quad = lane >> 4, l16 = lane & 15;

  #pragma unroll 1
  for (int l = 0; l < 3; ++l) {
    const _Float16* wL = wF123 + (((size_t)l * 4 + wave) << 14);
    const float* bia = (l == 0) ? b1 : (l == 1) ? b2 : b3;
    float bv[4];
    #pragma unroll
    for (int cb = 0; cb < 4; cb++) bv[cb] = bia[wave * 64 + cb * 16 + l16];
    f32x4 acc[8][4];
    #pragma unroll
    for (int i = 0; i < 8; i++)
      #pragma unroll
      for (int j = 0; j < 4; j++) {     // acc starts at bias: free bias add
        f32x4 z = {bv[j], bv[j], bv[j], bv[j]};
        acc[i][j] = z;
      }

    h8 bP[2][4];
    #pragma unroll
    for (int cb = 0; cb < 4; cb++) {    // B prefetch depth 2
      bP[0][cb] = *(const h8*)(wL + (((size_t)0 * 4 + cb) << 9) + lane * 8);
      bP[1][cb] = *(const h8*)(wL + (((size_t)1 * 4 + cb) << 9) + lane * 8);
    }

    #pragma unroll
    for (int ks = 0; ks < 8; ++ks) {
      int cur = ks & 1;
      int k0 = ks * 32 + quad * 8;
      h8 afr[8];
      #pragma unroll
      for (int rb = 0; rb < 8; rb++)
        afr[rb] = *(const h8*)(&hS[rb * 16 + l16][k0]);
      #pragma unroll
      for (int rb = 0; rb < 8; rb++)
        #pragma unroll
        for (int cb = 0; cb < 4; cb++)
          acc[rb][cb] = __builtin_amdgcn_mfma_f32_16x16x32_f16(afr[rb], bP[cur][cb], acc[rb][cb], 0, 0, 0);
      if (ks + 2 < 8) {                 // B for ks+2 into the slot just freed
        #pragma unroll
        for (int cb = 0; cb < 4; cb++)
          bP[cur][cb] = *(const h8*)(wL + (((size_t)(ks + 2) * 4 + cb) << 9) + lane * 8);
      }
    }
    __syncthreads();                    // all reads of hS complete
    #pragma unroll
    for (int rb = 0; rb < 8; rb++)
      #pragma unroll
      for (int cb = 0; cb < 4; cb++) {
        int n = wave * 64 + cb * 16 + l16;
        f32x4 a = acc[rb][cb];
        pk2 p01 = __builtin_amdgcn_cvt_pkrtz(fmaxf(a[0], 0.0f), fmaxf(a[1], 0.0f));
        pk2 p23 = __builtin_amdgcn_cvt_pkrtz(fmaxf(a[2], 0.0f), fmaxf(a[3], 0.0f));
        int m = rb * 16 + quad * 4;
        hS[m + 0][n] = (_Float16)p01[0];
        hS[m + 1][n] = (_Float16)p01[1];
        hS[m + 2][n] = (_Float16)p23[0];
        hS[m + 3][n] = (_Float16)p23[1];
      }
    __syncthreads();                    // writes visible before next reads
  }

  // ---- epilogue v2 (measured-best) ----
  // Phase A: weighted row-combine per query: hsum[q][c] = sum_j wgt*h3[q*8+j][c]
  {
    int q = tid >> 4, cpart = tid & 15;          // 16 threads/query, 16 cols each
    float accq[16];
    #pragma unroll
    for (int u = 0; u < 16; ++u) accq[u] = 0.0f;
    float sw = 0.0f;
    #pragma unroll
    for (int j = 0; j < 8; ++j) {
      int row = q * 8 + j;
      float w = mwL[row];
      sw += w;
      h8 a = *(const h8*)(&hS[row][cpart * 16]);
      h8 bq = *(const h8*)(&hS[row][cpart * 16 + 8]);
      #pragma unroll
      for (int u = 0; u < 8; ++u) {
        accq[u]     += w * (float)a[u];
        accq[8 + u] += w * (float)bq[u];
      }
    }
    __syncthreads();                    // all phase-A reads of hS done
    float* hsF = (float*)&hS[0][0];     // reuse LDS as [16][256] f32
    #pragma unroll
    for (int u = 0; u < 16; u += 4)
      *(f32x4*)(hsF + q * 256 + cpart * 16 + u) =
        f32x4{accq[u], accq[u+1], accq[u+2], accq[u+3]};
    if (cpart == 0) swL[q] = sw;
  }
  __syncthreads();
  // Phase B: matvec (Σwgt·h) @ w4
  if (tid < 192) {
    int q = tid / 12, r = tid % 12, j = r >> 2, part = r & 3;
    const float* hsF = (const float*)&hS[0][0];
    const float* hp = hsF + q * 256 + part * 64;
    const float* wp = w4T + j * 256 + part * 64;
    float s = 0.0f;
    #pragma unroll
    for (int u = 0; u < 64; ++u) s += hp[u] * wp[u];
    partB[q][j][part] = s;
  }
  __syncthreads();
  if (tid < 48) {
    int q = tid / 3, j = tid % 3;
    float o = partB[q][j][0] + partB[q][j][1] + partB[q][j][2] + partB[q][j][3]
            + b4[j] * swL[q];
    out[(size_t)(blockIdx.x * 16 + q) * 3 + j] = o;
  }
}

// ---------------------------------------------------------------------------
extern "C" void kernel_launch(void* const* d_in, const int* in_sizes, int n_in,
                              void* d_out, int out_size, void* d_ws, size_t ws_size,
                              hipStream_t stream)
{
  const float* feat  = (const float*)d_in[0];
  const float* attn  = (const float*)d_in[1];
  const float* coord = (const float*)d_in[2];
  const float* cell  = (const float*)d_in[3];
  const float* w0 = (const float*)d_in[4];
  const float* b0 = (const float*)d_in[5];
  const float* w1 = (const float*)d_in[6];
  const float* b1 = (const float*)d_in[7];
  const float* w2 = (const float*)d_in[8];
  const float* b2 = (const float*)d_in[9];
  const float* w3 = (const float*)d_in[10];
  const float* b3 = (const float*)d_in[11];
  const float* w4 = (const float*)d_in[12];
  const float* b4 = (const float*)d_in[13];
  float* out = (float*)d_out;           // reference output dtype = float32

  char* ws = (char*)d_ws;
  size_t off = 0;
  auto alloc = [&](size_t bytes) -> char* {
    char* p = ws + off;
    off += (bytes + 255) & ~(size_t)255;
    return p;
  };
  _Float16* featT = (_Float16*)alloc((size_t)B_ * H_ * W_ * D_ * 2);  //  2.10 MB
  _Float16* w0F   = (_Float16*)alloc((size_t)147456 * 2);             //  0.29 MB
  _Float16* wF123 = (_Float16*)alloc((size_t)196608 * 2);             //  0.39 MB
  float*  w4T   = (float*)alloc((size_t)3 * 256 * 4);
  float*  w0tl  = (float*)alloc((size_t)4 * 256 * 4);
  float*  attnT = (float*)alloc((size_t)B_ * S_ * HW_ * 4);           //  4.2 MB
  int*    segm  = (int*)alloc((size_t)B_ * HW_ * 4);                  //  64 KB
  int*    refc  = (int*)alloc((size_t)B_ * S_ * K_ * 4);
  float*  wprob = (float*)alloc((size_t)B_ * S_ * K_ * 4);
  _Float16* P0h = (_Float16*)alloc((size_t)B_ * HW_ * 256 * 2);       //  8.4 MB
  (void)in_sizes; (void)n_in; (void)out_size; (void)ws_size;          // ~16 MB total

  fused_prep_kernel<<<1927, 256, 0, stream>>>(feat, attn, w0, w1, w2, w3, w4,
                                              featT, attnT, w0F, wF123, w4T, w0tl, segm);
  topk_kernel<<<64, 256, 0, stream>>>(attnT, refc, wprob);
  p0_kernel<<<512, 256, 0, stream>>>(featT, w0F, P0h);
  trunk_kernel<<<2048, 256, 0, stream>>>(P0h, coord, cell, segm, refc, wprob,
                                         w0tl, b0, wF123, b1, b2, b3, w4T, b4, out);
}

// Round 16
// 244.485 us; speedup vs baseline: 1.2070x; 1.2070x over previous
//
#include <hip/hip_runtime.h>
#include <hip/hip_bf16.h>
#include <math.h>
#include <stdint.h>

#define B_ 4
#define D_ 64
#define H_ 64
#define W_ 64
#define S_ 64
#define N_ 8192
#define K_ 4
#define HID_ 256
#define HW_ 4096
#define NQ_ (B_*N_)        // 32768 queries
#define ROWS_ (NQ_*8)      // 262144 MLP rows (4 attn + 4 local per query)

typedef _Float16 h8   __attribute__((ext_vector_type(8)));
typedef _Float16 h4   __attribute__((ext_vector_type(4)));
typedef __fp16   pk2  __attribute__((ext_vector_type(2)));   // cvt_pkrtz native type
typedef float    f32x4 __attribute__((ext_vector_type(4)));

// ---------------------------------------------------------------------------
// fused prep (R10 structure, measured-best): [0,256) feat transpose |
// [256,512) attn transpose | [512,1863) weight repack | [1863,1927) segmax.
// ---------------------------------------------------------------------------
__global__ void fused_prep_kernel(const float* __restrict__ feat,
                                  const float* __restrict__ attn,
                                  const float* __restrict__ w0,
                                  const float* __restrict__ w1,
                                  const float* __restrict__ w2,
                                  const float* __restrict__ w3,
                                  const float* __restrict__ w4,
                                  _Float16* __restrict__ featT,
                                  float* __restrict__ attnT,
                                  _Float16* __restrict__ w0F,
                                  _Float16* __restrict__ wF123,
                                  float* __restrict__ w4T,
                                  float* __restrict__ w0tail,
                                  int* __restrict__ segm)
{
  __shared__ float t[64][65];
  int blk = blockIdx.x;
  int tid = threadIdx.x;

  if (blk < 256) {                       // ---- feat (B,D,H,W) -> featT[b][y][x][c]
    int b = blk >> 6, y = blk & 63;
    for (int p = 0; p < 16; ++p) {
      int c = p * 4 + (tid >> 6), x = tid & 63;
      t[c][x] = feat[(((size_t)b * 64 + c) << 12) + (y << 6) + x];
    }
    __syncthreads();
    for (int p = 0; p < 16; ++p) {
      int x = p * 4 + (tid >> 6), c = tid & 63;
      featT[((((size_t)b * 64 + y) * 64 + x) << 6) + c] = (_Float16)t[c][x];
    }
    return;
  }
  blk -= 256;
  if (blk < 256) {                       // ---- attn (B,HW,S) -> attnT (B,S,HW)
    int b = blk >> 6, j0 = (blk & 63) << 6;
    for (int idx = tid; idx < 4096; idx += 256) {
      int r = idx >> 6, c = idx & 63;
      t[r][c] = attn[((size_t)(b * 4096 + j0 + r)) * 64 + c];
    }
    __syncthreads();
    for (int idx = tid; idx < 4096; idx += 256) {
      int s = idx >> 6, r = idx & 63;
      attnT[((size_t)(b * 64 + s)) * 4096 + j0 + r] = t[r][s];
    }
    return;
  }
  blk -= 256;
  if (blk < 1351) {                      // ---- fragment-linear weights
    int i = blk * 256 + tid;
    if (i < 147456) {                    // w0F
      int g = i / 36864, rem = i - g * 36864;
      int ks = rem >> 11, rem2 = rem & 2047;
      int cb = rem2 >> 9, e = rem2 & 511;
      int lane = e >> 3, j = e & 7;
      int n = g * 64 + cb * 16 + (lane & 15);
      int k = ks * 32 + (lane >> 4) * 8 + j;       // reordered k = kk*64+cc
      int kk = k >> 6, cc = k & 63;
      w0F[i] = (_Float16)w0[(cc * 9 + kk) * 256 + n];
      return;
    }
    i -= 147456;
    if (i < 196608) {                    // wF123 (same layout; trunk uses it as
      int l = i >> 16, rem = i & 65535;  //  the A-operand / M=neurons now)
      int g = rem >> 14, rem2 = rem & 16383;
      int ks = rem2 >> 11, rem3 = rem2 & 2047;
      int cb = rem3 >> 9, e = rem3 & 511;
      int lane = e >> 3, j = e & 7;
      int n = g * 64 + cb * 16 + (lane & 15);
      int k = ks * 32 + (lane >> 4) * 8 + j;
      const float* w = (l == 0) ? w1 : (l == 1) ? w2 : w3;
      wF123[i] = (_Float16)w[k * 256 + n];
      return;
    }
    i -= 196608;
    if (i < 768) { int j = i / 256, c = i - j * 256; w4T[i] = w4[c * 3 + j]; return; }
    i -= 768;
    if (i < 1024) { int j = i >> 8, n = i & 255; w0tail[i] = w0[(576 + j) * 256 + n]; }
    return;
  }
  blk -= 1351;
  {                                      // ---- segmax (64 blocks)
    int p = blk * 256 + tid;
    if (p >= B_ * HW_) return;
    const float* a = attn + (size_t)p * S_;
    float best = a[0]; int bi = 0;
    for (int s = 1; s < S_; ++s) { float v = a[s]; if (v > best) { best = v; bi = s; } }
    segm[p] = bi;
  }
}

// ---------------------------------------------------------------------------
// topk v1 (measured-best): per (b,s) block, top-4 over 4096 px from attnT.
// ---------------------------------------------------------------------------
__global__ void topk_kernel(const float* __restrict__ attnT,
                            int* __restrict__ refc, float* __restrict__ wprob)
{
  int bid = blockIdx.x;                 // b*64 + s
  int tid = threadIdx.x;
  __shared__ float sv[256]; __shared__ int si[256];
  __shared__ float cvs[4]; __shared__ int cis[4];

  const float* col = attnT + (size_t)bid * 4096;
  float tv[4] = { -INFINITY, -INFINITY, -INFINITY, -INFINITY };
  int   ti[4] = { 0x7fffffff, 0x7fffffff, 0x7fffffff, 0x7fffffff };
  for (int j = tid; j < HW_; j += 256) {
    float v = col[j];
    if (v > tv[3]) {                    // equal value: existing (lower idx) wins
      tv[3] = v; ti[3] = j;
      #pragma unroll
      for (int x = 3; x > 0; --x) {
        if (tv[x] > tv[x-1] || (tv[x] == tv[x-1] && ti[x] < ti[x-1])) {
          float fv = tv[x]; tv[x] = tv[x-1]; tv[x-1] = fv;
          int   fi = ti[x]; ti[x] = ti[x-1]; ti[x-1] = fi;
        }
      }
    }
  }
  int ptr = 0;
  for (int r = 0; r < 4; ++r) {
    sv[tid] = (ptr < 4) ? tv[ptr] : -INFINITY;
    si[tid] = (ptr < 4) ? ti[ptr] : 0x7fffffff;
    __syncthreads();
    for (int o = 128; o; o >>= 1) {
      if (tid < o) {
        float v2 = sv[tid + o]; int i2 = si[tid + o];
        if (v2 > sv[tid] || (v2 == sv[tid] && i2 < si[tid])) { sv[tid] = v2; si[tid] = i2; }
      }
      __syncthreads();
    }
    if (tid == 0) { cvs[r] = sv[0]; cis[r] = si[0]; }
    __syncthreads();
    if (ptr < 4 && ti[ptr] == cis[r]) ptr++;
    __syncthreads();
  }
  if (tid == 0) {
    float ssum = cvs[0] + cvs[1] + cvs[2] + cvs[3];
    for (int k = 0; k < 4; ++k) { refc[bid*4 + k] = cis[k]; wprob[bid*4 + k] = cvs[k] / ssum; }
  }
}

// ---------------------------------------------------------------------------
// P0 GEMM (f16 MFMA, f16 out): 512 blocks = (b, y, half-row of 32 px).
// ---------------------------------------------------------------------------
__launch_bounds__(256, 2)
__global__ void p0_kernel(const _Float16* __restrict__ featT,
                          const _Float16* __restrict__ w0F,
                          _Float16* __restrict__ P0h)
{
  int blk = blockIdx.x;                 // b*128 + y*2 + hr
  int b = blk >> 7, y = (blk >> 1) & 63, hr = blk & 1;
  int tid = threadIdx.x;
  int wave = tid >> 6, lane = tid & 63, quad = lane >> 4, l16 = lane & 15;

  f32x4 acc[2][4];
  #pragma unroll
  for (int i = 0; i < 2; i++)
    #pragma unroll
    for (int j = 0; j < 4; j++) { f32x4 z = {0.f,0.f,0.f,0.f}; acc[i][j] = z; }
  h8 zero8 = {0,0,0,0,0,0,0,0};

  #pragma unroll
  for (int ks = 0; ks < 18; ++ks) {     // K = 576 = 18*32
    int k0 = ks * 32 + quad * 8;
    int kk = k0 >> 6, cc = k0 & 63;
    int di = kk / 3 - 1, dj = kk - (kk / 3) * 3 - 1;
    int yy = y + di;
    h8 afr[2];
    #pragma unroll
    for (int rb = 0; rb < 2; rb++) {
      int xx = hr * 32 + rb * 16 + l16 + dj;
      if ((unsigned)yy < 64u && (unsigned)xx < 64u)
        afr[rb] = *(const h8*)(featT + ((((size_t)b * 64 + yy) * 64 + xx) << 6) + cc);
      else
        afr[rb] = zero8;
    }
    h8 bfr[4];
    #pragma unroll
    for (int cb = 0; cb < 4; cb++)
      bfr[cb] = *(const h8*)(w0F + ((((size_t)wave * 18 + ks) * 4 + cb) << 9) + lane * 8);
    #pragma unroll
    for (int rb = 0; rb < 2; rb++)
      #pragma unroll
      for (int cb = 0; cb < 4; cb++)
        acc[rb][cb] = __builtin_amdgcn_mfma_f32_16x16x32_f16(afr[rb], bfr[cb], acc[rb][cb], 0, 0, 0);
  }
  int pixbase = b * 4096 + y * 64 + hr * 32;
  #pragma unroll
  for (int rb = 0; rb < 2; rb++)
    #pragma unroll
    for (int cb = 0; cb < 4; cb++)
      #pragma unroll
      for (int i = 0; i < 4; i++) {
        int m = rb * 16 + quad * 4 + i;
        int n = wave * 64 + cb * 16 + l16;
        P0h[((size_t)(pixbase + m) << 8) + n] = (_Float16)acc[rb][cb][i];
      }
}

// ---------------------------------------------------------------------------
// Fused MLP trunk, M=128, OPERAND-SWAPPED MFMA: A=weights (M=neurons),
// B=activations (N=data rows). C-layout then gives each lane 4 consecutive
// neurons for a fixed row -> packed 8B ds_write_b64 writeback (was 4 scalar
// 2B writes) and float4 bias init. B-frag LDS reads keep the proven
// ds_read_b128 pattern. Meta fused in preamble; epilogue v2.
// ---------------------------------------------------------------------------
__launch_bounds__(256, 2)
__global__ void trunk_kernel(const _Float16* __restrict__ P0h,
                             const float* __restrict__ coord,
                             const float* __restrict__ cell,
                             const int* __restrict__ segm,
                             const int* __restrict__ refc,
                             const float* __restrict__ wprob,
                             const float* __restrict__ w0tail,
                             const float* __restrict__ b0,
                             const _Float16* __restrict__ wF123,
                             const float* __restrict__ b1,
                             const float* __restrict__ b2,
                             const float* __restrict__ b3,
                             const float* __restrict__ w4T,
                             const float* __restrict__ b4,
                             float* __restrict__ out)
{
  __shared__ _Float16 hS[128][264];     // +8 pad; 67.6 KB
  __shared__ float  mwL[128];
  __shared__ int    msrcL[128];
  __shared__ float4 mtL[128];
  __shared__ float  swL[16];
  __shared__ float  partB[16][3][4];

  int tid = threadIdx.x;
  int wv = tid >> 6;

  // ---- meta preamble: threads 0..15 build 8 row descriptors each ----
  if (tid < 16) {
    int q = blockIdx.x * 16 + tid;
    int b = q >> 13;
    float c0 = coord[2*q], c1 = coord[2*q + 1];
    float rc0 = cell[2*q] * 64.0f, rc1 = cell[2*q + 1] * 64.0f;   // rel_cell

    // attention branch
    float pf0 = (c0 + 1.0f) / 2.0f * 64.0f;
    float pf1 = (c1 + 1.0f) / 2.0f * 64.0f;
    int pc0 = (int)pf0, pc1 = (int)pf1;         // trunc (non-negative)
    pc0 = min(max(pc0, 0), 4095); pc1 = min(max(pc1, 0), 4095);
    int pc1d = pc0 * 64 + pc1;
    int sg = segm[b * 4096 + min(pc1d, 4095)];
    int base = (b * 64 + sg) * 4;
    #pragma unroll
    for (int k = 0; k < 4; ++k) {
      int rc = refc[base + k];
      int rrc = rc - pc1d;
      float rel0 = (float)(rrc >> 6) * 0.015625f;   // floor-div 64 then /64
      float rel1 = (float)(rrc & 63) * 0.015625f;
      int rr = tid * 8 + k;
      msrcL[rr] = rc;                              // batch-0 gather (faithful)
      mtL[rr] = make_float4(rel0, rel1, rc0, rc1);
      mwL[rr] = 0.5f * wprob[base + k];
    }

    // local ensemble branch
    const float sg0[4] = { -1.f, -1.f, 1.f, 1.f };
    const float sg1[4] = { -1.f,  1.f, -1.f, 1.f };
    float area[4], rr0[4], rr1[4]; int srcs[4];
    #pragma unroll
    for (int t = 0; t < 4; ++t) {
      float o0 = sg0[t] * 0.015625f + 1e-6f;
      float o1 = sg1[t] * 0.015625f + 1e-6f;
      float cc0 = fminf(fmaxf(c0 + o0, -1.0f + 1e-6f), 1.0f - 1e-6f);
      float cc1 = fminf(fmaxf(c1 + o1, -1.0f + 1e-6f), 1.0f - 1e-6f);
      float vy = ((cc0 + 1.0f) * 64.0f - 1.0f) / 2.0f;
      float vx = ((cc1 + 1.0f) * 64.0f - 1.0f) / 2.0f;
      float fy = fminf(fmaxf(rintf(vy), 0.0f), 63.0f);   // rint then clip
      float fx = fminf(fmaxf(rintf(vx), 0.0f), 63.0f);
      int iy = (int)fy, ix = (int)fx;
      srcs[t] = b * 4096 + iy * 64 + ix;
      float qc0 = -1.0f + (2.0f * (float)iy + 1.0f) / 64.0f;
      float qc1 = -1.0f + (2.0f * (float)ix + 1.0f) / 64.0f;
      float r0 = (c0 - qc0) * 64.0f;
      float r1 = (c1 - qc1) * 64.0f;
      rr0[t] = r0; rr1[t] = r1;
      area[t] = fabsf(r0 * r1) + 1e-9f;
    }
    float tot = area[0] + area[1] + area[2] + area[3];
    #pragma unroll
    for (int t = 0; t < 4; ++t) {
      int rr = tid * 8 + 4 + t;
      msrcL[rr] = srcs[t];
      mtL[rr] = make_float4(rr0[t], rr1[t], rc0, rc1);
      mwL[rr] = 0.5f * area[3 - t] / tot;          // wts = area[::-1]/tot
    }
  }
  __syncthreads();

  // ---- seed: h0 = relu(P0h[src] + t . w0tail + b0); 8-deep batched gather ----
  {
    int cg = tid & 63;
    float4 wt0 = ((const float4*)w0tail)[cg];
    float4 wt1 = ((const float4*)w0tail)[64 + cg];
    float4 wt2 = ((const float4*)w0tail)[128 + cg];
    float4 wt3 = ((const float4*)w0tail)[192 + cg];
    float4 bb  = ((const float4*)b0)[cg];
    #pragma unroll 1
    for (int g = 0; g < 4; ++g) {
      int srcs[8]; float4 ts[8];
      #pragma unroll
      for (int i = 0; i < 8; ++i) {
        int rr_ = g * 32 + i * 4 + wv;
        srcs[i] = msrcL[rr_];
        ts[i] = mtL[rr_];
      }
      #pragma unroll
      for (int i = 0; i < 8; ++i) {
        int rr = g * 32 + i * 4 + wv;
        float4 t = ts[i];
        h4 pvv = *(const h4*)(P0h + ((size_t)srcs[i] << 8) + cg * 4);
        float v0 = fmaxf((float)pvv[0] + t.x*wt0.x + t.y*wt1.x + t.z*wt2.x + t.w*wt3.x + bb.x, 0.0f);
        float v1 = fmaxf((float)pvv[1] + t.x*wt0.y + t.y*wt1.y + t.z*wt2.y + t.w*wt3.y + bb.y, 0.0f);
        float v2 = fmaxf((float)pvv[2] + t.x*wt0.z + t.y*wt1.z + t.z*wt2.z + t.w*wt3.z + bb.z, 0.0f);
        float v3 = fmaxf((float)pvv[3] + t.x*wt0.w + t.y*wt1.w + t.z*wt2.w + t.w*wt3.w + bb.w, 0.0f);
        pk2 a01 = __builtin_amdgcn_cvt_pkrtz(v0, v1);
        pk2 a23 = __builtin_amdgcn_cvt_pkrtz(v2, v3);
        int2 packed;
        packed.x = __builtin_bit_cast(int, a01);
        packed.y = __builtin_bit_cast(int, a23);
        *(int2*)(&hS[rr][cg * 4]) = packed;
      }
    }
  }
  __syncthreads();

  int wave = tid >> 6, lane = tid & 63, quad = lane >> 4, l16 = lane & 15;

  #pragma unroll 1
  for (int l = 0; l < 3; ++l) {
    const _Float16* wL = wF123 + (((size_t)l * 4 + wave) << 14);
    const float* bia = (l == 0) ? b1 : (l == 1) ? b2 : b3;
    // bias as float4 per (mb): neurons wave*64 + mb*16 + quad*4 + {0..3}
    f32x4 bvv[4];
    #pragma unroll
    for (int mb = 0; mb < 4; mb++)
      bvv[mb] = *(const f32x4*)(bia + wave * 64 + mb * 16 + quad * 4);
    f32x4 acc[4][8];                    // [mb (neurons)][nb (row blocks)]
    #pragma unroll
    for (int mb = 0; mb < 4; mb++)
      #pragma unroll
      for (int nb = 0; nb < 8; nb++)
        acc[mb][nb] = bvv[mb];          // bias rides the matrix pipe

    h8 wP[2][4];                        // weight A-frag prefetch depth 2
    #pragma unroll
    for (int mb = 0; mb < 4; mb++) {
      wP[0][mb] = *(const h8*)(wL + (((size_t)0 * 4 + mb) << 9) + lane * 8);
      wP[1][mb] = *(const h8*)(wL + (((size_t)1 * 4 + mb) << 9) + lane * 8);
    }

    #pragma unroll
    for (int ks = 0; ks < 8; ++ks) {
      int cur = ks & 1;
      int k0 = ks * 32 + quad * 8;
      h8 hfr[8];                        // activation B-frags from LDS
      #pragma unroll
      for (int nb = 0; nb < 8; nb++)
        hfr[nb] = *(const h8*)(&hS[nb * 16 + l16][k0]);
      #pragma unroll
      for (int mb = 0; mb < 4; mb++)
        #pragma unroll
        for (int nb = 0; nb < 8; nb++)
          acc[mb][nb] = __builtin_amdgcn_mfma_f32_16x16x32_f16(wP[cur][mb], hfr[nb], acc[mb][nb], 0, 0, 0);
      if (ks + 2 < 8) {                 // weights for ks+2 into freed slot
        #pragma unroll
        for (int mb = 0; mb < 4; mb++)
          wP[cur][mb] = *(const h8*)(wL + (((size_t)(ks + 2) * 4 + mb) << 9) + lane * 8);
      }
    }
    __syncthreads();                    // all reads of hS complete
    // packed writeback: lane holds row nb*16+l16, neurons wave*64+mb*16+quad*4+{0..3}
    #pragma unroll
    for (int mb = 0; mb < 4; mb++)
      #pragma unroll
      for (int nb = 0; nb < 8; nb++) {
        f32x4 a = acc[mb][nb];
        pk2 p01 = __builtin_amdgcn_cvt_pkrtz(fmaxf(a[0], 0.0f), fmaxf(a[1], 0.0f));
        pk2 p23 = __builtin_amdgcn_cvt_pkrtz(fmaxf(a[2], 0.0f), fmaxf(a[3], 0.0f));
        int2 packed;
        packed.x = __builtin_bit_cast(int, p01);
        packed.y = __builtin_bit_cast(int, p23);
        int row = nb * 16 + l16;
        int ncol = wave * 64 + mb * 16 + quad * 4;
        *(int2*)(&hS[row][ncol]) = packed;    // one 8B write (was 4 scalar)
      }
    __syncthreads();                    // writes visible before next reads
  }

  // ---- epilogue v2 (measured-best) ----
  // Phase A: weighted row-combine per query: hsum[q][c] = sum_j wgt*h3[q*8+j][c]
  {
    int q = tid >> 4, cpart = tid & 15;          // 16 threads/query, 16 cols each
    float accq[16];
    #pragma unroll
    for (int u = 0; u < 16; ++u) accq[u] = 0.0f;
    float sw = 0.0f;
    #pragma unroll
    for (int j = 0; j < 8; ++j) {
      int row = q * 8 + j;
      float w = mwL[row];
      sw += w;
      h8 a = *(const h8*)(&hS[row][cpart * 16]);
      h8 bq = *(const h8*)(&hS[row][cpart * 16 + 8]);
      #pragma unroll
      for (int u = 0; u < 8; ++u) {
        accq[u]     += w * (float)a[u];
        accq[8 + u] += w * (float)bq[u];
      }
    }
    __syncthreads();                    // all phase-A reads of hS done
    float* hsF = (float*)&hS[0][0];     // reuse LDS as [16][256] f32
    #pragma unroll
    for (int u = 0; u < 16; u += 4)
      *(f32x4*)(hsF + q * 256 + cpart * 16 + u) =
        f32x4{accq[u], accq[u+1], accq[u+2], accq[u+3]};
    if (cpart == 0) swL[q] = sw;
  }
  __syncthreads();
  // Phase B: matvec (Σwgt·h) @ w4
  if (tid < 192) {
    int q = tid / 12, r = tid % 12, j = r >> 2, part = r & 3;
    const float* hsF = (const float*)&hS[0][0];
    const float* hp = hsF + q * 256 + part * 64;
    const float* wp = w4T + j * 256 + part * 64;
    float s = 0.0f;
    #pragma unroll
    for (int u = 0; u < 64; ++u) s += hp[u] * wp[u];
    partB[q][j][part] = s;
  }
  __syncthreads();
  if (tid < 48) {
    int q = tid / 3, j = tid % 3;
    float o = partB[q][j][0] + partB[q][j][1] + partB[q][j][2] + partB[q][j][3]
            + b4[j] * swL[q];
    out[(size_t)(blockIdx.x * 16 + q) * 3 + j] = o;
  }
}

// ---------------------------------------------------------------------------
extern "C" void kernel_launch(void* const* d_in, const int* in_sizes, int n_in,
                              void* d_out, int out_size, void* d_ws, size_t ws_size,
                              hipStream_t stream)
{
  const float* feat  = (const float*)d_in[0];
  const float* attn  = (const float*)d_in[1];
  const float* coord = (const float*)d_in[2];
  const float* cell  = (const float*)d_in[3];
  const float* w0 = (const float*)d_in[4];
  const float* b0 = (const float*)d_in[5];
  const float* w1 = (const float*)d_in[6];
  const float* b1 = (const float*)d_in[7];
  const float* w2 = (const float*)d_in[8];
  const float* b2 = (const float*)d_in[9];
  const float* w3 = (const float*)d_in[10];
  const float* b3 = (const float*)d_in[11];
  const float* w4 = (const float*)d_in[12];
  const float* b4 = (const float*)d_in[13];
  float* out = (float*)d_out;           // reference output dtype = float32

  char* ws = (char*)d_ws;
  size_t off = 0;
  auto alloc = [&](size_t bytes) -> char* {
    char* p = ws + off;
    off += (bytes + 255) & ~(size_t)255;
    return p;
  };
  _Float16* featT = (_Float16*)alloc((size_t)B_ * H_ * W_ * D_ * 2);  //  2.10 MB
  _Float16* w0F   = (_Float16*)alloc((size_t)147456 * 2);             //  0.29 MB
  _Float16* wF123 = (_Float16*)alloc((size_t)196608 * 2);             //  0.39 MB
  float*  w4T   = (float*)alloc((size_t)3 * 256 * 4);
  float*  w0tl  = (float*)alloc((size_t)4 * 256 * 4);
  float*  attnT = (float*)alloc((size_t)B_ * S_ * HW_ * 4);           //  4.2 MB
  int*    segm  = (int*)alloc((size_t)B_ * HW_ * 4);                  //  64 KB
  int*    refc  = (int*)alloc((size_t)B_ * S_ * K_ * 4);
  float*  wprob = (float*)alloc((size_t)B_ * S_ * K_ * 4);
  _Float16* P0h = (_Float16*)alloc((size_t)B_ * HW_ * 256 * 2);       //  8.4 MB
  (void)in_sizes; (void)n_in; (void)out_size; (void)ws_size;          // ~16 MB total

  fused_prep_kernel<<<1927, 256, 0, stream>>>(feat, attn, w0, w1, w2, w3, w4,
                                              featT, attnT, w0F, wF123, w4T, w0tl, segm);
  topk_kernel<<<256, 256, 0, stream>>>(attnT, refc, wprob);
  p0_kernel<<<512, 256, 0, stream>>>(featT, w0F, P0h);
  trunk_kernel<<<2048, 256, 0, stream>>>(P0h, coord, cell, segm, refc, wprob,
                                         w0tl, b0, wF123, b1, b2, b3, w4T, b4, out);
}